// Round 4
// baseline (751.583 us; speedup 1.0000x reference)
//
#include <hip/hip_runtime.h>
#include <math.h>

// Problem constants
#define FD   256
#define NH   4
#define SP3  8
#define NP   32          // SP3*NH aux points per query
#define EDIM 64          // FD/NH
#define H    128
#define NS   1024
#define BS   4
#define QT   16          // queries per tile-block (featk / epik)

#define TEX         (H*H)              // 16384 texels per (plane,b)
#define BATCH_ELEMS (TEX*FD)           // 4,194,304 floats
#define PAIR_B      2                  // batches processed per pass
#define PAIR_Q      (PAIR_B*NS)        // 2048 queries per pass
#define PPLANE      (PAIR_B*BATCH_ELEMS) // per-plane elems in pair buffer

// ---- workspace layout (float offsets). Total 28,508,160 floats = 114.03 MB.
// ws_size proven >= 114 MB (round 3 passed); 228 MB overflowed (round 2).
#define WS_PLANES 0
#define WS_FEAT   (3*PPLANE)                       // [2048][256]
#define WS_QK     (WS_FEAT + PAIR_Q*FD)            // [2048][256]
#define WS_AUX    (WS_QK   + PAIR_Q*FD)            // [2048][96]
#define WS_WF     (WS_AUX  + PAIR_Q*NP*3)          // [2048][4][256]

// ---------------------------------------------------------------------------
// K1: transpose planes [B,C,H,W] -> [b-pair][H*W,C] (channel-last).
// ---------------------------------------------------------------------------
__global__ __launch_bounds__(256) void tpk2(
    const float* __restrict__ xz, const float* __restrict__ xy,
    const float* __restrict__ yz, float* __restrict__ dstAll, int b0)
{
  int bid = blockIdx.x;
  int tT = bid & 255; bid >>= 8;     // 256 texel-tiles of 64
  int bl = bid & 1;   bid >>= 1;     // local batch in pair
  int pl = bid;                      // plane
  const float* src = pl == 0 ? xz : (pl == 1 ? xy : yz);
  float* dst = dstAll + (size_t)pl * PPLANE + (size_t)bl * BATCH_ELEMS;
  int b = b0 + bl;

  __shared__ float T[64 * 260];      // T[texel][channel], stride 260
  int lane = threadIdx.x & 63, w = threadIdx.x >> 6;
  int lrow = lane >> 4;              // 0..3
  int ltex = (lane & 15) << 2;       // 0,4,..,60

  const float* sbase = src + (size_t)b * FD * TEX + tT * 64;
  #pragma unroll
  for (int i = 0; i < 16; i++) {
    int c = i * 16 + w * 4 + lrow;   // covers 0..255
    float4 v = *(const float4*)(sbase + (size_t)c * TEX + ltex);
    T[(ltex + 0) * 260 + c] = v.x;
    T[(ltex + 1) * 260 + c] = v.y;
    T[(ltex + 2) * 260 + c] = v.z;
    T[(ltex + 3) * 260 + c] = v.w;
  }
  __syncthreads();
  #pragma unroll
  for (int i = 0; i < 16; i++) {
    int t = w * 16 + i;
    float4 v = *(const float4*)(&T[t * 260 + lane * 4]);
    *(float4*)(dst + (size_t)(tT * 64 + t) * FD + lane * 4) = v;  // 1KB/wave
  }
}

// ---------------------------------------------------------------------------
// Bilinear helpers (channel-last plane)
// ---------------------------------------------------------------------------
__device__ __forceinline__ float sample_plane(const float* __restrict__ p,
                                              float u, float v) {
  float x = fminf(fmaxf(u, 0.f), 1.f) * (float)(H - 1);
  float y = fminf(fmaxf(v, 0.f), 1.f) * (float)(H - 1);
  float xf = floorf(x), yf = floorf(y);
  int x0 = (int)xf, y0 = (int)yf;
  float wx = x - xf, wy = y - yf;
  int dx = (x0 < H - 1) ? FD : 0;
  int dy = (y0 < H - 1) ? H * FD : 0;
  int i00 = (y0 * H + x0) * FD;
  float f00 = p[i00], f01 = p[i00 + dx], f10 = p[i00 + dy], f11 = p[i00 + dy + dx];
  float a = f00 + wx * (f01 - f00);
  float b = f10 + wx * (f11 - f10);
  return a + wy * (b - a);
}

__device__ __forceinline__ void setup_samp(int* si, float* sw, float u, float v) {
  float x = fminf(fmaxf(u, 0.f), 1.f) * (float)(H - 1);
  float y = fminf(fmaxf(v, 0.f), 1.f) * (float)(H - 1);
  float xf = floorf(x), yf = floorf(y);
  int x0 = (int)xf, y0 = (int)yf;
  float wx = x - xf, wy = y - yf;
  si[0] = (y0 * H + x0) * FD;
  si[1] = (x0 < H - 1) ? FD : 0;
  si[2] = (y0 < H - 1) ? H * FD : 0;
  sw[0] = (1.f - wy) * (1.f - wx);
  sw[1] = (1.f - wy) * wx;
  sw[2] = wy * (1.f - wx);
  sw[3] = wy * wx;
}

// ---------------------------------------------------------------------------
// K2: per 16-query tile: feature sampling + offsets/aux + q-projection + qk.
// qk[q][c] = sum_e q_scaled[e] * w_k[c][e];  (q . b_k cancels in softmax)
// ---------------------------------------------------------------------------
__global__ __launch_bounds__(256) void featk(
    const float* __restrict__ qpos, const float* __restrict__ planesT,
    const float* __restrict__ w_off, const float* __restrict__ b_off,
    const float* __restrict__ w_q, const float* __restrict__ b_q,
    const float* __restrict__ w_k,
    float* __restrict__ feat, float* __restrict__ aux, float* __restrict__ qk,
    int b0)
{
  const int tid = threadIdx.x;
  const int q0l = blockIdx.x * QT;          // local query base in pair
  const int bl = q0l >> 10;                 // local batch
  __shared__ float s_feat[QT * 260];
  __shared__ float s_q[QT * 68];

  const float* Pxz = planesT + 0 * (size_t)PPLANE + (size_t)bl * BATCH_ELEMS + tid;
  const float* Pxy = planesT + 1 * (size_t)PPLANE + (size_t)bl * BATCH_ELEMS + tid;
  const float* Pyz = planesT + 2 * (size_t)PPLANE + (size_t)bl * BATCH_ELEMS + tid;

  for (int qs = 0; qs < QT; qs++) {
    size_t qg = (size_t)b0 * NS + q0l + qs; // global query for qpos
    float px = qpos[qg * 3 + 0], py = qpos[qg * 3 + 1], pz = qpos[qg * 3 + 2];
    float f = sample_plane(Pxz, px, pz) + sample_plane(Pxy, px, py)
            + sample_plane(Pyz, py, pz);
    s_feat[qs * 260 + tid] = f;
    feat[(size_t)(q0l + qs) * FD + tid] = f;
  }
  __syncthreads();

  // offsets -> aux. thread t<192: half=t/96 handles 8 queries for column j.
  if (tid < 192) {
    int half = tid / 96, j = tid - half * 96;
    float acc[8];
    float bj = b_off[j];
    #pragma unroll
    for (int k = 0; k < 8; k++) acc[k] = bj;
    for (int c = 0; c < FD; c++) {
      float wv = w_off[c * 96 + j];
      #pragma unroll
      for (int k = 0; k < 8; k++)
        acc[k] = fmaf(s_feat[(half * 8 + k) * 260 + c], wv, acc[k]);
    }
    int d = j % 3;
    #pragma unroll
    for (int k = 0; k < 8; k++) {
      int qs = half * 8 + k;
      size_t qg = (size_t)b0 * NS + q0l + qs;
      aux[(size_t)(q0l + qs) * 96 + j] = acc[k] + qpos[qg * 3 + d];
    }
  }
  // q projection (scaled by sqrt(E)=8); wave g handles queries g*4+k
  {
    int e = tid & 63, g = tid >> 6;
    #pragma unroll
    for (int k = 0; k < 4; k++) {
      int qs = g * 4 + k;
      float a = b_q[e];
      for (int c = 0; c < FD; c++)
        a = fmaf(s_feat[qs * 260 + c], w_q[c * EDIM + e], a);
      s_q[qs * 68 + e] = a * 8.0f;
    }
  }
  __syncthreads();
  // qk: thread owns channel tid; w_k row contiguous (float4)
  {
    float acc[QT];
    #pragma unroll
    for (int qs = 0; qs < QT; qs++) acc[qs] = 0.f;
    const float4* wk4 = reinterpret_cast<const float4*>(w_k + (size_t)tid * EDIM);
    for (int e4 = 0; e4 < EDIM / 4; e4++) {
      float4 wv = wk4[e4];
      int e = e4 * 4;
      #pragma unroll
      for (int qs = 0; qs < QT; qs++) {
        acc[qs] = fmaf(s_q[qs * 68 + e + 0], wv.x, acc[qs]);
        acc[qs] = fmaf(s_q[qs * 68 + e + 1], wv.y, acc[qs]);
        acc[qs] = fmaf(s_q[qs * 68 + e + 2], wv.z, acc[qs]);
        acc[qs] = fmaf(s_q[qs * 68 + e + 3], wv.w, acc[qs]);
      }
    }
    #pragma unroll
    for (int qs = 0; qs < QT; qs++)
      qk[(size_t)(q0l + qs) * FD + tid] = acc[qs];
  }
}

// ---------------------------------------------------------------------------
// K3 (hot): one query per block, wave-per-point float4 layout.
// Lane l of every wave owns channels 4l..4l+3. Wave w handles points
// p = w*8 .. w*8+7; each corner read = one 1KB global_load_dwordx4 / wave.
// sim dot reduces entirely within the wave; af stays in VGPRs.
// ---------------------------------------------------------------------------
__global__ __launch_bounds__(256, 4) void attnk(
    const float* __restrict__ planesT, const float* __restrict__ aux,
    const float* __restrict__ qk, float* __restrict__ wf)
{
  const int tid = threadIdx.x, lane = tid & 63, w = tid >> 6;
  const int q = blockIdx.x;                 // local query in pair
  const int bl = q >> 10;
  const int c4 = lane * 4;

  __shared__ int   s_si[96][3];
  __shared__ float s_sw[96][4];
  __shared__ float s_sim[NP];
  __shared__ float s_attn[NP];
  __shared__ float4 s_wp[16 * 64];          // [wave][head][lane]

  const float* P0 = planesT + 0 * (size_t)PPLANE + (size_t)bl * BATCH_ELEMS + c4;
  const float* P1 = planesT + 1 * (size_t)PPLANE + (size_t)bl * BATCH_ELEMS + c4;
  const float* P2 = planesT + 2 * (size_t)PPLANE + (size_t)bl * BATCH_ELEMS + c4;

  if (tid < 96) {
    int p = tid / 3, pl = tid - p * 3;
    float ax = aux[(size_t)q * 96 + p * 3 + 0];
    float ay = aux[(size_t)q * 96 + p * 3 + 1];
    float az = aux[(size_t)q * 96 + p * 3 + 2];
    float u = (pl == 2) ? ay : ax;   // pl0:(ax,az) pl1:(ax,ay) pl2:(ay,az)
    float v = (pl == 1) ? ay : az;
    setup_samp(s_si[tid], s_sw[tid], u, v);
  }
  float4 qk4 = *(const float4*)(qk + (size_t)q * FD + c4);
  __syncthreads();

  float4 afr[8];
  #pragma unroll 2
  for (int k = 0; k < 8; k++) {
    int p = w * 8 + k;
    float4 a; a.x = 0.f; a.y = 0.f; a.z = 0.f; a.w = 0.f;
    #pragma unroll
    for (int pl = 0; pl < 3; pl++) {
      const float* P = pl == 0 ? P0 : (pl == 1 ? P1 : P2);
      int i00 = s_si[p * 3 + pl][0];
      int dxo = s_si[p * 3 + pl][1];
      int dyo = s_si[p * 3 + pl][2];
      float w0 = s_sw[p * 3 + pl][0], w1 = s_sw[p * 3 + pl][1];
      float w2 = s_sw[p * 3 + pl][2], w3 = s_sw[p * 3 + pl][3];
      float4 f00 = *(const float4*)(P + i00);
      float4 f01 = *(const float4*)(P + i00 + dxo);
      float4 f10 = *(const float4*)(P + i00 + dyo);
      float4 f11 = *(const float4*)(P + i00 + dyo + dxo);
      a.x = fmaf(w0, f00.x, fmaf(w1, f01.x, fmaf(w2, f10.x, fmaf(w3, f11.x, a.x))));
      a.y = fmaf(w0, f00.y, fmaf(w1, f01.y, fmaf(w2, f10.y, fmaf(w3, f11.y, a.y))));
      a.z = fmaf(w0, f00.z, fmaf(w1, f01.z, fmaf(w2, f10.z, fmaf(w3, f11.z, a.z))));
      a.w = fmaf(w0, f00.w, fmaf(w1, f01.w, fmaf(w2, f10.w, fmaf(w3, f11.w, a.w))));
    }
    afr[k] = a;
    float t = fmaf(qk4.x, a.x, fmaf(qk4.y, a.y, fmaf(qk4.z, a.z, qk4.w * a.w)));
    #pragma unroll
    for (int o = 32; o >= 1; o >>= 1) t += __shfl_xor(t, o, 64);
    if (lane == 0) s_sim[p] = t;
  }
  __syncthreads();

  if (tid < NH) {   // softmax over j for head h=tid (points p = j*NH + h)
    float sim[SP3], m = -1e30f;
    #pragma unroll
    for (int j = 0; j < SP3; j++) { sim[j] = s_sim[j * NH + tid]; m = fmaxf(m, sim[j]); }
    float sum = 0.f, e_[SP3];
    #pragma unroll
    for (int j = 0; j < SP3; j++) { e_[j] = __expf(sim[j] - m); sum += e_[j]; }
    float inv = 1.0f / sum;
    #pragma unroll
    for (int j = 0; j < SP3; j++) s_attn[j * NH + tid] = e_[j] * inv;
  }
  __syncthreads();

  // per-wave partial wf: acc[h] over this wave's 8 points (2 per head)
  float4 acc[NH];
  #pragma unroll
  for (int h = 0; h < NH; h++) { acc[h].x = 0.f; acc[h].y = 0.f; acc[h].z = 0.f; acc[h].w = 0.f; }
  #pragma unroll
  for (int k = 0; k < 8; k++) {
    int p = w * 8 + k, h = p & 3;
    float a = s_attn[p];
    acc[h].x = fmaf(a, afr[k].x, acc[h].x);
    acc[h].y = fmaf(a, afr[k].y, acc[h].y);
    acc[h].z = fmaf(a, afr[k].z, acc[h].z);
    acc[h].w = fmaf(a, afr[k].w, acc[h].w);
  }
  #pragma unroll
  for (int h = 0; h < NH; h++) s_wp[(w * 4 + h) * 64 + lane] = acc[h];
  __syncthreads();

  { // wave w sums partials for head h=w and stores 1KB
    float4 r0 = s_wp[(0 * 4 + w) * 64 + lane];
    float4 r1 = s_wp[(1 * 4 + w) * 64 + lane];
    float4 r2 = s_wp[(2 * 4 + w) * 64 + lane];
    float4 r3 = s_wp[(3 * 4 + w) * 64 + lane];
    float4 r; r.x = r0.x + r1.x + r2.x + r3.x;
    r.y = r0.y + r1.y + r2.y + r3.y;
    r.z = r0.z + r1.z + r2.z + r3.z;
    r.w = r0.w + r1.w + r2.w + r3.w;
    *(float4*)(wf + ((size_t)q * NH + w) * FD + c4) = r;
  }
}

// ---------------------------------------------------------------------------
// K4: epilogue per 16-query tile: o = per-head wf@w_v + b_v (w_v via L1),
// then out = o@w_out + b_out + feat (w_out streamed once per block).
// ---------------------------------------------------------------------------
__global__ __launch_bounds__(256) void epik(
    const float* __restrict__ wf, const float* __restrict__ feat,
    const float* __restrict__ w_v, const float* __restrict__ b_v,
    const float* __restrict__ w_out, const float* __restrict__ b_out,
    float* __restrict__ out, int b0)
{
  const int tid = threadIdx.x;
  const int q0l = blockIdx.x * QT;
  __shared__ float s_o[QT * 257];

  { // phase A: o[qs][h*64+e]; wave = head h, lane = e
    int h = tid >> 6, e = tid & 63;
    float acc[QT];
    float bv = b_v[e];
    #pragma unroll
    for (int qs = 0; qs < QT; qs++) acc[qs] = bv;
    const float* wrow = wf + ((size_t)q0l * NH + h) * FD;
    for (int c = 0; c < FD; c++) {
      float wv = w_v[c * EDIM + e];
      #pragma unroll
      for (int qs = 0; qs < QT; qs++)
        acc[qs] = fmaf(wrow[(size_t)qs * NH * FD + c], wv, acc[qs]);
    }
    #pragma unroll
    for (int qs = 0; qs < QT; qs++) s_o[qs * 257 + h * EDIM + e] = acc[qs];
  }
  __syncthreads();

  { // phase B: out[q][d] = sum_c o[q][c] w_out[c][d] + b_out[d] + feat[q][d]
    float r[QT];
    float bo = b_out[tid];
    #pragma unroll
    for (int qs = 0; qs < QT; qs++) r[qs] = bo;
    for (int c = 0; c < FD; c++) {
      float wv = w_out[(size_t)c * FD + tid];
      #pragma unroll
      for (int qs = 0; qs < QT; qs++)
        r[qs] = fmaf(s_o[qs * 257 + c], wv, r[qs]);
    }
    #pragma unroll
    for (int qs = 0; qs < QT; qs++)
      out[((size_t)b0 * NS + q0l + qs) * FD + tid]
          = r[qs] + feat[(size_t)(q0l + qs) * FD + tid];
  }
}

// ---------------------------------------------------------------------------
extern "C" void kernel_launch(void* const* d_in, const int* in_sizes, int n_in,
                              void* d_out, int out_size, void* d_ws, size_t ws_size,
                              hipStream_t stream) {
  const float* qp    = (const float*)d_in[0];
  const float* cxz   = (const float*)d_in[1];
  const float* cxy   = (const float*)d_in[2];
  const float* cyz   = (const float*)d_in[3];
  const float* w_off = (const float*)d_in[4];
  const float* b_off = (const float*)d_in[5];
  const float* w_q   = (const float*)d_in[6];
  const float* b_q   = (const float*)d_in[7];
  const float* w_k   = (const float*)d_in[8];
  const float* b_k   = (const float*)d_in[9];   (void)b_k; // cancels in softmax
  const float* w_v   = (const float*)d_in[10];
  const float* b_v   = (const float*)d_in[11];
  const float* w_out = (const float*)d_in[12];
  const float* b_out = (const float*)d_in[13];
  float* out = (float*)d_out;
  (void)in_sizes; (void)n_in; (void)out_size; (void)ws_size;

  float* ws      = (float*)d_ws;
  float* planesT = ws + WS_PLANES;
  float* feat    = ws + WS_FEAT;
  float* qk      = ws + WS_QK;
  float* aux     = ws + WS_AUX;
  float* wf      = ws + WS_WF;

  for (int pair = 0; pair < BS / PAIR_B; ++pair) {
    int b0 = pair * PAIR_B;
    hipLaunchKernelGGL(tpk2, dim3(3 * PAIR_B * 256), dim3(256), 0, stream,
                       cxz, cxy, cyz, planesT, b0);
    hipLaunchKernelGGL(featk, dim3(PAIR_Q / QT), dim3(256), 0, stream,
                       qp, planesT, w_off, b_off, w_q, b_q, w_k,
                       feat, aux, qk, b0);
    hipLaunchKernelGGL(attnk, dim3(PAIR_Q), dim3(256), 0, stream,
                       planesT, aux, qk, wf);
    hipLaunchKernelGGL(epik, dim3(PAIR_Q / QT), dim3(256), 0, stream,
                       wf, feat, w_v, b_v, w_out, b_out, out, b0);
  }
}

// Round 5
// 552.876 us; speedup vs baseline: 1.3594x; 1.3594x over previous
//
#include <hip/hip_runtime.h>
#include <math.h>

// Problem constants
#define FD   256
#define NH   4
#define SP3  8
#define NP   32          // SP3*NH aux points per query
#define EDIM 64          // FD/NH
#define H    128
#define NS   1024
#define BS   4
#define QT   8           // queries per tile-block (featk / epik)

#define TEX         (H*H)              // 16384 texels per (plane,b)
#define BATCH_ELEMS (TEX*FD)           // 4,194,304 floats
#define PAIR_B      2                  // batches processed per pass
#define PAIR_Q      (PAIR_B*NS)        // 2048 queries per pass
#define PPLANE      (PAIR_B*BATCH_ELEMS) // per-plane elems in pair buffer

// ---- workspace layout (float offsets). Total ~114.05 MB.
// ws_size proven >= 114 MB (round 3 passed); 228 MB overflowed (round 2).
#define WS_PLANES 0
#define WS_FEAT   (3*PPLANE)                       // [2048][256]
#define WS_QK     (WS_FEAT + PAIR_Q*FD)            // [2048][256]
#define WS_AUX    (WS_QK   + PAIR_Q*FD)            // [2048][96]
#define WS_WF     (WS_AUX  + PAIR_Q*NP*3)          // [2048][4][256]
#define WS_PERM   (WS_WF   + PAIR_Q*NH*FD)         // [2 pairs][2048] uint

// ---------------------------------------------------------------------------
// K1: transpose planes [B,C,H,W] -> [b-pair][H*W,C] (channel-last).
// ---------------------------------------------------------------------------
__global__ __launch_bounds__(256) void tpk2(
    const float* __restrict__ xz, const float* __restrict__ xy,
    const float* __restrict__ yz, float* __restrict__ dstAll, int b0)
{
  int bid = blockIdx.x;
  int tT = bid & 255; bid >>= 8;     // 256 texel-tiles of 64
  int bl = bid & 1;   bid >>= 1;     // local batch in pair
  int pl = bid;                      // plane
  const float* src = pl == 0 ? xz : (pl == 1 ? xy : yz);
  float* dst = dstAll + (size_t)pl * PPLANE + (size_t)bl * BATCH_ELEMS;
  int b = b0 + bl;

  __shared__ float T[64 * 260];      // T[texel][channel], stride 260
  int lane = threadIdx.x & 63, w = threadIdx.x >> 6;
  int lrow = lane >> 4;              // 0..3
  int ltex = (lane & 15) << 2;       // 0,4,..,60

  const float* sbase = src + (size_t)b * FD * TEX + tT * 64;
  #pragma unroll
  for (int i = 0; i < 16; i++) {
    int c = i * 16 + w * 4 + lrow;   // covers 0..255
    float4 v = *(const float4*)(sbase + (size_t)c * TEX + ltex);
    T[(ltex + 0) * 260 + c] = v.x;
    T[(ltex + 1) * 260 + c] = v.y;
    T[(ltex + 2) * 260 + c] = v.z;
    T[(ltex + 3) * 260 + c] = v.w;
  }
  __syncthreads();
  #pragma unroll
  for (int i = 0; i < 16; i++) {
    int t = w * 16 + i;
    float4 v = *(const float4*)(&T[t * 260 + lane * 4]);
    *(float4*)(dst + (size_t)(tT * 64 + t) * FD + lane * 4) = v;  // 1KB/wave
  }
}

// ---------------------------------------------------------------------------
// K1b: Morton-sort the pair's 2048 queries by (batch, interleaved xyz) key.
// One block per pair; bitonic sort of (key<<32|idx) in LDS. Any permutation
// is correctness-neutral for attnk — the sort only buys L2 locality.
// ---------------------------------------------------------------------------
__device__ __forceinline__ unsigned mort7(unsigned v) {   // 7 bits -> every 3rd
  unsigned r = 0;
  #pragma unroll
  for (int i = 0; i < 7; i++) r |= ((v >> i) & 1u) << (3 * i);
  return r;
}

__global__ __launch_bounds__(1024) void sortk(
    const float* __restrict__ qpos, unsigned* __restrict__ perm)
{
  const int pair = blockIdx.x;
  const int b0 = pair * PAIR_B;
  const int t = threadIdx.x;
  __shared__ unsigned long long s_kv[PAIR_Q];   // 16 KB

  for (int i = t; i < PAIR_Q; i += 1024) {
    size_t qg = (size_t)b0 * NS + i;
    float x = fminf(fmaxf(qpos[qg * 3 + 0], 0.f), 1.f);
    float y = fminf(fmaxf(qpos[qg * 3 + 1], 0.f), 1.f);
    float z = fminf(fmaxf(qpos[qg * 3 + 2], 0.f), 1.f);
    unsigned xi = (unsigned)(x * 127.0f);
    unsigned yi = (unsigned)(y * 127.0f);
    unsigned zi = (unsigned)(z * 127.0f);
    unsigned key = ((unsigned)(i >> 10) << 21)
                 | (mort7(xi) << 2) | (mort7(yi) << 1) | mort7(zi);
    s_kv[i] = ((unsigned long long)key << 32) | (unsigned)i;
  }
  for (unsigned k = 2; k <= PAIR_Q; k <<= 1) {
    for (unsigned j = k >> 1; j > 0; j >>= 1) {
      __syncthreads();
      for (int i = t; i < PAIR_Q; i += 1024) {
        int ixj = i ^ (int)j;
        if (ixj > i) {
          unsigned long long a = s_kv[i], b = s_kv[ixj];
          bool asc = ((i & (int)k) == 0);
          if ((a > b) == asc) { s_kv[i] = b; s_kv[ixj] = a; }
        }
      }
    }
  }
  __syncthreads();
  for (int i = t; i < PAIR_Q; i += 1024)
    perm[(size_t)pair * PAIR_Q + i] = (unsigned)(s_kv[i] & 0xFFFFFFFFu);
}

// ---------------------------------------------------------------------------
// Bilinear helpers (channel-last plane)
// ---------------------------------------------------------------------------
__device__ __forceinline__ float sample_plane(const float* __restrict__ p,
                                              float u, float v) {
  float x = fminf(fmaxf(u, 0.f), 1.f) * (float)(H - 1);
  float y = fminf(fmaxf(v, 0.f), 1.f) * (float)(H - 1);
  float xf = floorf(x), yf = floorf(y);
  int x0 = (int)xf, y0 = (int)yf;
  float wx = x - xf, wy = y - yf;
  int dx = (x0 < H - 1) ? FD : 0;
  int dy = (y0 < H - 1) ? H * FD : 0;
  int i00 = (y0 * H + x0) * FD;
  float f00 = p[i00], f01 = p[i00 + dx], f10 = p[i00 + dy], f11 = p[i00 + dy + dx];
  float a = f00 + wx * (f01 - f00);
  float b = f10 + wx * (f11 - f10);
  return a + wy * (b - a);
}

__device__ __forceinline__ void setup_samp(int* si, float* sw, float u, float v) {
  float x = fminf(fmaxf(u, 0.f), 1.f) * (float)(H - 1);
  float y = fminf(fmaxf(v, 0.f), 1.f) * (float)(H - 1);
  float xf = floorf(x), yf = floorf(y);
  int x0 = (int)xf, y0 = (int)yf;
  float wx = x - xf, wy = y - yf;
  si[0] = (y0 * H + x0) * FD;
  si[1] = (x0 < H - 1) ? FD : 0;
  si[2] = (y0 < H - 1) ? H * FD : 0;
  sw[0] = (1.f - wy) * (1.f - wx);
  sw[1] = (1.f - wy) * wx;
  sw[2] = wy * (1.f - wx);
  sw[3] = wy * wx;
}

// ---------------------------------------------------------------------------
// K2: per 8-query tile: feature sampling + offsets/aux + q-projection + qk.
// qk[q][c] = sum_e q_scaled[e] * w_k[c][e];  (q . b_k cancels in softmax)
// ---------------------------------------------------------------------------
__global__ __launch_bounds__(256) void featk(
    const float* __restrict__ qpos, const float* __restrict__ planesT,
    const float* __restrict__ w_off, const float* __restrict__ b_off,
    const float* __restrict__ w_q, const float* __restrict__ b_q,
    const float* __restrict__ w_k,
    float* __restrict__ feat, float* __restrict__ aux, float* __restrict__ qk,
    int b0)
{
  const int tid = threadIdx.x;
  const int q0l = blockIdx.x * QT;          // local query base in pair
  const int bl = q0l >> 10;                 // local batch
  __shared__ float s_feat[QT * 260];
  __shared__ float s_q[QT * 68];

  const float* Pxz = planesT + 0 * (size_t)PPLANE + (size_t)bl * BATCH_ELEMS + tid;
  const float* Pxy = planesT + 1 * (size_t)PPLANE + (size_t)bl * BATCH_ELEMS + tid;
  const float* Pyz = planesT + 2 * (size_t)PPLANE + (size_t)bl * BATCH_ELEMS + tid;

  for (int qs = 0; qs < QT; qs++) {
    size_t qg = (size_t)b0 * NS + q0l + qs; // global query for qpos
    float px = qpos[qg * 3 + 0], py = qpos[qg * 3 + 1], pz = qpos[qg * 3 + 2];
    float f = sample_plane(Pxz, px, pz) + sample_plane(Pxy, px, py)
            + sample_plane(Pyz, py, pz);
    s_feat[qs * 260 + tid] = f;
    feat[(size_t)(q0l + qs) * FD + tid] = f;
  }
  __syncthreads();

  // offsets -> aux. thread t<192: half=t/96 handles 4 queries for column j.
  if (tid < 192) {
    int half = tid / 96, j = tid - half * 96;
    float acc[4];
    float bj = b_off[j];
    #pragma unroll
    for (int k = 0; k < 4; k++) acc[k] = bj;
    for (int c = 0; c < FD; c++) {
      float wv = w_off[c * 96 + j];
      #pragma unroll
      for (int k = 0; k < 4; k++)
        acc[k] = fmaf(s_feat[(half * 4 + k) * 260 + c], wv, acc[k]);
    }
    int d = j % 3;
    #pragma unroll
    for (int k = 0; k < 4; k++) {
      int qs = half * 4 + k;
      size_t qg = (size_t)b0 * NS + q0l + qs;
      aux[(size_t)(q0l + qs) * 96 + j] = acc[k] + qpos[qg * 3 + d];
    }
  }
  // q projection (scaled by sqrt(E)=8); wave g handles queries g*2, g*2+1
  {
    int e = tid & 63, g = tid >> 6;
    #pragma unroll
    for (int k = 0; k < 2; k++) {
      int qs = g * 2 + k;
      float a = b_q[e];
      for (int c = 0; c < FD; c++)
        a = fmaf(s_feat[qs * 260 + c], w_q[c * EDIM + e], a);
      s_q[qs * 68 + e] = a * 8.0f;
    }
  }
  __syncthreads();
  // qk: thread owns channel tid; w_k row contiguous (float4)
  {
    float acc[QT];
    #pragma unroll
    for (int qs = 0; qs < QT; qs++) acc[qs] = 0.f;
    const float4* wk4 = reinterpret_cast<const float4*>(w_k + (size_t)tid * EDIM);
    for (int e4 = 0; e4 < EDIM / 4; e4++) {
      float4 wv = wk4[e4];
      int e = e4 * 4;
      #pragma unroll
      for (int qs = 0; qs < QT; qs++) {
        acc[qs] = fmaf(s_q[qs * 68 + e + 0], wv.x, acc[qs]);
        acc[qs] = fmaf(s_q[qs * 68 + e + 1], wv.y, acc[qs]);
        acc[qs] = fmaf(s_q[qs * 68 + e + 2], wv.z, acc[qs]);
        acc[qs] = fmaf(s_q[qs * 68 + e + 3], wv.w, acc[qs]);
      }
    }
    #pragma unroll
    for (int qs = 0; qs < QT; qs++)
      qk[(size_t)(q0l + qs) * FD + tid] = acc[qs];
  }
}

// ---------------------------------------------------------------------------
// K3 (hot): one query per block, wave-per-point float4 gathers, af in LDS
// (no register spill). Query chosen via Morton perm + XCD swizzle so each
// XCD works a compact spatial region (L2 locality).
// ---------------------------------------------------------------------------
__global__ __launch_bounds__(256) void attnk(
    const float* __restrict__ planesT, const float* __restrict__ aux,
    const float* __restrict__ qk, const unsigned* __restrict__ perm,
    float* __restrict__ wf)
{
  const int tid = threadIdx.x, lane = tid & 63, w = tid >> 6;
  const int bid = blockIdx.x;
  const int q = (int)perm[((bid & 7) << 8) | (bid >> 3)]; // local query in pair
  const int bl = q >> 10;
  const int c4 = lane * 4;

  __shared__ int   s_si[96][3];
  __shared__ float s_sw[96][4];
  __shared__ float s_sim[NP];
  __shared__ float s_attn[NP];
  __shared__ float4 s_af[NP * 64];          // 32 KB: [point][lane]

  const float* P0 = planesT + 0 * (size_t)PPLANE + (size_t)bl * BATCH_ELEMS + c4;
  const float* P1 = planesT + 1 * (size_t)PPLANE + (size_t)bl * BATCH_ELEMS + c4;
  const float* P2 = planesT + 2 * (size_t)PPLANE + (size_t)bl * BATCH_ELEMS + c4;

  if (tid < 96) {
    int p = tid / 3, pl = tid - p * 3;
    float ax = aux[(size_t)q * 96 + p * 3 + 0];
    float ay = aux[(size_t)q * 96 + p * 3 + 1];
    float az = aux[(size_t)q * 96 + p * 3 + 2];
    float u = (pl == 2) ? ay : ax;   // pl0:(ax,az) pl1:(ax,ay) pl2:(ay,az)
    float v = (pl == 1) ? ay : az;
    setup_samp(s_si[tid], s_sw[tid], u, v);
  }
  float4 qk4 = *(const float4*)(qk + (size_t)q * FD + c4);
  __syncthreads();

  #pragma unroll 2
  for (int k = 0; k < 8; k++) {
    int p = w * 8 + k;
    float4 a; a.x = 0.f; a.y = 0.f; a.z = 0.f; a.w = 0.f;
    #pragma unroll
    for (int pl = 0; pl < 3; pl++) {
      const float* P = pl == 0 ? P0 : (pl == 1 ? P1 : P2);
      int i00 = s_si[p * 3 + pl][0];
      int dxo = s_si[p * 3 + pl][1];
      int dyo = s_si[p * 3 + pl][2];
      float w0 = s_sw[p * 3 + pl][0], w1 = s_sw[p * 3 + pl][1];
      float w2 = s_sw[p * 3 + pl][2], w3 = s_sw[p * 3 + pl][3];
      float4 f00 = *(const float4*)(P + i00);
      float4 f01 = *(const float4*)(P + i00 + dxo);
      float4 f10 = *(const float4*)(P + i00 + dyo);
      float4 f11 = *(const float4*)(P + i00 + dyo + dxo);
      a.x = fmaf(w0, f00.x, fmaf(w1, f01.x, fmaf(w2, f10.x, fmaf(w3, f11.x, a.x))));
      a.y = fmaf(w0, f00.y, fmaf(w1, f01.y, fmaf(w2, f10.y, fmaf(w3, f11.y, a.y))));
      a.z = fmaf(w0, f00.z, fmaf(w1, f01.z, fmaf(w2, f10.z, fmaf(w3, f11.z, a.z))));
      a.w = fmaf(w0, f00.w, fmaf(w1, f01.w, fmaf(w2, f10.w, fmaf(w3, f11.w, a.w))));
    }
    s_af[p * 64 + lane] = a;
    float t = fmaf(qk4.x, a.x, fmaf(qk4.y, a.y, fmaf(qk4.z, a.z, qk4.w * a.w)));
    #pragma unroll
    for (int o = 32; o >= 1; o >>= 1) t += __shfl_xor(t, o, 64);
    if (lane == 0) s_sim[p] = t;
  }
  __syncthreads();

  if (tid < NH) {   // softmax over j for head h=tid (points p = j*NH + h)
    float sim[SP3], m = -1e30f;
    #pragma unroll
    for (int j = 0; j < SP3; j++) { sim[j] = s_sim[j * NH + tid]; m = fmaxf(m, sim[j]); }
    float sum = 0.f, e_[SP3];
    #pragma unroll
    for (int j = 0; j < SP3; j++) { e_[j] = __expf(sim[j] - m); sum += e_[j]; }
    float inv = 1.0f / sum;
    #pragma unroll
    for (int j = 0; j < SP3; j++) s_attn[j * NH + tid] = e_[j] * inv;
  }
  __syncthreads();

  { // wave w computes head h=w: wf = sum_j attn[j*4+w] * af[j*4+w]
    float4 r; r.x = 0.f; r.y = 0.f; r.z = 0.f; r.w = 0.f;
    #pragma unroll
    for (int j = 0; j < SP3; j++) {
      int p = j * NH + w;
      float a = s_attn[p];
      float4 f = s_af[p * 64 + lane];
      r.x = fmaf(a, f.x, r.x);
      r.y = fmaf(a, f.y, r.y);
      r.z = fmaf(a, f.z, r.z);
      r.w = fmaf(a, f.w, r.w);
    }
    *(float4*)(wf + ((size_t)q * NH + w) * FD + c4) = r;
  }
}

// ---------------------------------------------------------------------------
// K4: epilogue per 8-query tile: o = per-head wf@w_v + b_v (w_v in LDS),
// then out = o@w_out + b_out + feat (w_out streamed once per block).
// ---------------------------------------------------------------------------
__global__ __launch_bounds__(256) void epik(
    const float* __restrict__ wf, const float* __restrict__ feat,
    const float* __restrict__ w_v, const float* __restrict__ b_v,
    const float* __restrict__ w_out, const float* __restrict__ b_out,
    float* __restrict__ out, int b0)
{
  const int tid = threadIdx.x;
  const int q0l = blockIdx.x * QT;
  __shared__ float s_wv[FD * EDIM];   // 64 KB, [c][e]
  __shared__ float s_o[QT * 257];

  {
    const float4* src4 = (const float4*)w_v;
    float4* dst4 = (float4*)s_wv;
    #pragma unroll
    for (int i = 0; i < (FD * EDIM / 4) / 256; i++)
      dst4[tid + 256 * i] = src4[tid + 256 * i];
  }
  __syncthreads();

  { // phase A: o[qs][h*64+e]
    int h = tid >> 6, e = tid & 63;
    float acc[QT];
    float bv = b_v[e];
    #pragma unroll
    for (int qs = 0; qs < QT; qs++) acc[qs] = bv;
    const float* wrow = wf + ((size_t)q0l * NH + h) * FD;
    for (int c = 0; c < FD; c++) {
      float wv = s_wv[c * EDIM + e];
      #pragma unroll
      for (int qs = 0; qs < QT; qs++)
        acc[qs] = fmaf(wrow[(size_t)qs * NH * FD + c], wv, acc[qs]);
    }
    #pragma unroll
    for (int qs = 0; qs < QT; qs++) s_o[qs * 257 + h * EDIM + e] = acc[qs];
  }
  __syncthreads();

  { // phase B: out[q][d] = sum_c o[q][c] w_out[c][d] + b_out[d] + feat[q][d]
    float r[QT];
    float bo = b_out[tid];
    #pragma unroll
    for (int qs = 0; qs < QT; qs++) r[qs] = bo;
    for (int c = 0; c < FD; c++) {
      float wv = w_out[(size_t)c * FD + tid];
      #pragma unroll
      for (int qs = 0; qs < QT; qs++)
        r[qs] = fmaf(s_o[qs * 257 + c], wv, r[qs]);
    }
    #pragma unroll
    for (int qs = 0; qs < QT; qs++)
      out[((size_t)b0 * NS + q0l + qs) * FD + tid]
          = r[qs] + feat[(size_t)(q0l + qs) * FD + tid];
  }
}

// ---------------------------------------------------------------------------
extern "C" void kernel_launch(void* const* d_in, const int* in_sizes, int n_in,
                              void* d_out, int out_size, void* d_ws, size_t ws_size,
                              hipStream_t stream) {
  const float* qp    = (const float*)d_in[0];
  const float* cxz   = (const float*)d_in[1];
  const float* cxy   = (const float*)d_in[2];
  const float* cyz   = (const float*)d_in[3];
  const float* w_off = (const float*)d_in[4];
  const float* b_off = (const float*)d_in[5];
  const float* w_q   = (const float*)d_in[6];
  const float* b_q   = (const float*)d_in[7];
  const float* w_k   = (const float*)d_in[8];
  const float* b_k   = (const float*)d_in[9];   (void)b_k; // cancels in softmax
  const float* w_v   = (const float*)d_in[10];
  const float* b_v   = (const float*)d_in[11];
  const float* w_out = (const float*)d_in[12];
  const float* b_out = (const float*)d_in[13];
  float* out = (float*)d_out;
  (void)in_sizes; (void)n_in; (void)out_size; (void)ws_size;

  float* ws      = (float*)d_ws;
  float* planesT = ws + WS_PLANES;
  float* feat    = ws + WS_FEAT;
  float* qk      = ws + WS_QK;
  float* aux     = ws + WS_AUX;
  float* wf      = ws + WS_WF;
  unsigned* perm = (unsigned*)(ws + WS_PERM);

  hipLaunchKernelGGL(sortk, dim3(BS / PAIR_B), dim3(1024), 0, stream, qp, perm);

  for (int pair = 0; pair < BS / PAIR_B; ++pair) {
    int b0 = pair * PAIR_B;
    hipLaunchKernelGGL(tpk2, dim3(3 * PAIR_B * 256), dim3(256), 0, stream,
                       cxz, cxy, cyz, planesT, b0);
    hipLaunchKernelGGL(featk, dim3(PAIR_Q / QT), dim3(256), 0, stream,
                       qp, planesT, w_off, b_off, w_q, b_q, w_k,
                       feat, aux, qk, b0);
    hipLaunchKernelGGL(attnk, dim3(PAIR_Q), dim3(256), 0, stream,
                       planesT, aux, qk, perm + (size_t)pair * PAIR_Q, wf);
    hipLaunchKernelGGL(epik, dim3(PAIR_Q / QT), dim3(256), 0, stream,
                       wf, feat, w_v, b_v, w_out, b_out, out, b0);
  }
}

// Round 6
// 540.494 us; speedup vs baseline: 1.3905x; 1.0229x over previous
//
#include <hip/hip_runtime.h>
#include <math.h>

// Problem constants
#define FD   256
#define NH   4
#define SP3  8
#define NP   32          // SP3*NH aux points per query
#define EDIM 64          // FD/NH
#define H    128
#define NS   1024
#define BS   4
#define QT   8           // queries per tile-block (featk / epik)

#define TEX         (H*H)              // 16384 texels per (plane,b)
#define BATCH_ELEMS (TEX*FD)           // 4,194,304 floats
#define PAIR_B      2                  // batches processed per pass
#define PAIR_Q      (PAIR_B*NS)        // 2048 queries per pass
#define PPLANE      (PAIR_B*BATCH_ELEMS) // per-plane elems in pair buffer

// ---- workspace layout (float offsets). Total ~114.05 MB.
// ws_size proven >= 114 MB (rounds 3/5 passed); 228 MB overflowed (round 2).
#define WS_PLANES 0
#define WS_FEAT   (3*PPLANE)                       // [2048][256]
#define WS_QK     (WS_FEAT + PAIR_Q*FD)            // [2048][256]
#define WS_AUX    (WS_QK   + PAIR_Q*FD)            // [2048][96]
#define WS_WF     (WS_AUX  + PAIR_Q*NP*3)          // [2048][4][256]
#define WS_PERM   (WS_WF   + PAIR_Q*NH*FD)         // [2 pairs][2048] uint

// bf16 helpers (round-to-nearest-even). Used ONLY on the wf path (af after
// the fp32 sim dot) — sim-path quantization is amplified ~176x and is fatal.
__device__ __forceinline__ unsigned short f2bf(float f) {
  unsigned b = __float_as_uint(f);
  return (unsigned short)((b + 0x7FFFu + ((b >> 16) & 1u)) >> 16);
}
__device__ __forceinline__ float bf2f(unsigned short u) {
  return __uint_as_float(((unsigned)u) << 16);
}

// ---------------------------------------------------------------------------
// K1: transpose planes [B,C,H,W] -> [b-pair][H*W,C] (channel-last).
// 32-texel x 256-channel tiles; LDS 33 KB -> 4 blocks/CU.
// ---------------------------------------------------------------------------
__global__ __launch_bounds__(256) void tpk2(
    const float* __restrict__ xz, const float* __restrict__ xy,
    const float* __restrict__ yz, float* __restrict__ dstAll, int b0)
{
  int bid = blockIdx.x;
  int tT = bid & 511; bid >>= 9;     // 512 texel-tiles of 32
  int bl = bid & 1;   bid >>= 1;     // local batch in pair
  int pl = bid;                      // plane
  const float* src = pl == 0 ? xz : (pl == 1 ? xy : yz);
  float* dst = dstAll + (size_t)pl * PPLANE + (size_t)bl * BATCH_ELEMS;
  int b = b0 + bl;

  __shared__ float T[32 * 260];      // T[texel][channel], stride 260
  int lane = threadIdx.x & 63, w = threadIdx.x >> 6;
  int tex4 = (lane & 7) * 4;         // 0,4,..,28
  int csub = lane >> 3;              // 0..7

  const float* sbase = src + (size_t)b * FD * TEX + tT * 32;
  #pragma unroll
  for (int i = 0; i < 8; i++) {
    int c = i * 32 + w * 8 + csub;   // covers 0..255
    float4 v = *(const float4*)(sbase + (size_t)c * TEX + tex4);
    T[(tex4 + 0) * 260 + c] = v.x;
    T[(tex4 + 1) * 260 + c] = v.y;
    T[(tex4 + 2) * 260 + c] = v.z;
    T[(tex4 + 3) * 260 + c] = v.w;
  }
  __syncthreads();
  #pragma unroll
  for (int i = 0; i < 8; i++) {
    int t = w * 8 + i;
    float4 v = *(const float4*)(&T[t * 260 + lane * 4]);
    *(float4*)(dst + (size_t)(tT * 32 + t) * FD + lane * 4) = v;  // 1KB/wave
  }
}

// ---------------------------------------------------------------------------
// K1b: counting-sort the pair's 2048 queries into 256 buckets =
// (batch<<7)|top-7-Morton-bits. Any permutation is correctness-neutral;
// bucket granularity (~8 queries/cell) is all the locality we measured to
// matter. One block per pair, O(n), ~3 barriers.
// ---------------------------------------------------------------------------
__device__ __forceinline__ unsigned mort7(unsigned v) {   // 7 bits -> every 3rd
  unsigned r = 0;
  #pragma unroll
  for (int i = 0; i < 7; i++) r |= ((v >> i) & 1u) << (3 * i);
  return r;
}

__global__ __launch_bounds__(1024) void sortk(
    const float* __restrict__ qpos, unsigned* __restrict__ perm)
{
  const int pair = blockIdx.x;
  const int b0 = pair * PAIR_B;
  const int t = threadIdx.x;
  __shared__ unsigned cnt[256];
  __shared__ unsigned base[256];
  if (t < 256) cnt[t] = 0;
  __syncthreads();
  unsigned myb[2];
  #pragma unroll
  for (int r = 0; r < 2; r++) {
    int i = t + r * 1024;
    size_t qg = (size_t)b0 * NS + i;
    float x = fminf(fmaxf(qpos[qg * 3 + 0], 0.f), 1.f);
    float y = fminf(fmaxf(qpos[qg * 3 + 1], 0.f), 1.f);
    float z = fminf(fmaxf(qpos[qg * 3 + 2], 0.f), 1.f);
    unsigned m = (mort7((unsigned)(x * 127.f)) << 2)
               | (mort7((unsigned)(y * 127.f)) << 1)
               |  mort7((unsigned)(z * 127.f));          // 21 bits
    unsigned bkt = ((unsigned)(i >> 10) << 7) | (m >> 14);
    myb[r] = bkt;
    atomicAdd(&cnt[bkt], 1u);
  }
  __syncthreads();
  if (t == 0) {
    unsigned s = 0;
    for (int k = 0; k < 256; k++) { base[k] = s; s += cnt[k]; }
  }
  __syncthreads();
  #pragma unroll
  for (int r = 0; r < 2; r++) {
    int i = t + r * 1024;
    unsigned pos = atomicAdd(&base[myb[r]], 1u);
    perm[(size_t)pair * PAIR_Q + pos] = (unsigned)i;
  }
}

// ---------------------------------------------------------------------------
// Bilinear helpers (channel-last plane)
// ---------------------------------------------------------------------------
__device__ __forceinline__ float sample_plane(const float* __restrict__ p,
                                              float u, float v) {
  float x = fminf(fmaxf(u, 0.f), 1.f) * (float)(H - 1);
  float y = fminf(fmaxf(v, 0.f), 1.f) * (float)(H - 1);
  float xf = floorf(x), yf = floorf(y);
  int x0 = (int)xf, y0 = (int)yf;
  float wx = x - xf, wy = y - yf;
  int dx = (x0 < H - 1) ? FD : 0;
  int dy = (y0 < H - 1) ? H * FD : 0;
  int i00 = (y0 * H + x0) * FD;
  float f00 = p[i00], f01 = p[i00 + dx], f10 = p[i00 + dy], f11 = p[i00 + dy + dx];
  float a = f00 + wx * (f01 - f00);
  float b = f10 + wx * (f11 - f10);
  return a + wy * (b - a);
}

__device__ __forceinline__ void setup_samp(int* si, float* sw, float u, float v) {
  float x = fminf(fmaxf(u, 0.f), 1.f) * (float)(H - 1);
  float y = fminf(fmaxf(v, 0.f), 1.f) * (float)(H - 1);
  float xf = floorf(x), yf = floorf(y);
  int x0 = (int)xf, y0 = (int)yf;
  float wx = x - xf, wy = y - yf;
  si[0] = (y0 * H + x0) * FD;
  si[1] = (x0 < H - 1) ? FD : 0;
  si[2] = (y0 < H - 1) ? H * FD : 0;
  sw[0] = (1.f - wy) * (1.f - wx);
  sw[1] = (1.f - wy) * wx;
  sw[2] = wy * (1.f - wx);
  sw[3] = wy * wx;
}

// ---------------------------------------------------------------------------
// K2: per 8-query tile: feature sampling + offsets/aux + q-projection + qk.
// qk[q][c] = sum_e q_scaled[e] * w_k[c][e];  (q . b_k cancels in softmax)
// ---------------------------------------------------------------------------
__global__ __launch_bounds__(256) void featk(
    const float* __restrict__ qpos, const float* __restrict__ planesT,
    const float* __restrict__ w_off, const float* __restrict__ b_off,
    const float* __restrict__ w_q, const float* __restrict__ b_q,
    const float* __restrict__ w_k,
    float* __restrict__ feat, float* __restrict__ aux, float* __restrict__ qk,
    int b0)
{
  const int tid = threadIdx.x;
  const int q0l = blockIdx.x * QT;          // local query base in pair
  const int bl = q0l >> 10;                 // local batch
  __shared__ float s_feat[QT * 260];
  __shared__ float s_q[QT * 68];

  const float* Pxz = planesT + 0 * (size_t)PPLANE + (size_t)bl * BATCH_ELEMS + tid;
  const float* Pxy = planesT + 1 * (size_t)PPLANE + (size_t)bl * BATCH_ELEMS + tid;
  const float* Pyz = planesT + 2 * (size_t)PPLANE + (size_t)bl * BATCH_ELEMS + tid;

  for (int qs = 0; qs < QT; qs++) {
    size_t qg = (size_t)b0 * NS + q0l + qs; // global query for qpos
    float px = qpos[qg * 3 + 0], py = qpos[qg * 3 + 1], pz = qpos[qg * 3 + 2];
    float f = sample_plane(Pxz, px, pz) + sample_plane(Pxy, px, py)
            + sample_plane(Pyz, py, pz);
    s_feat[qs * 260 + tid] = f;
    feat[(size_t)(q0l + qs) * FD + tid] = f;
  }
  __syncthreads();

  // offsets -> aux. thread t<192: half=t/96 handles 4 queries for column j.
  if (tid < 192) {
    int half = tid / 96, j = tid - half * 96;
    float acc[4];
    float bj = b_off[j];
    #pragma unroll
    for (int k = 0; k < 4; k++) acc[k] = bj;
    for (int c = 0; c < FD; c++) {
      float wv = w_off[c * 96 + j];
      #pragma unroll
      for (int k = 0; k < 4; k++)
        acc[k] = fmaf(s_feat[(half * 4 + k) * 260 + c], wv, acc[k]);
    }
    int d = j % 3;
    #pragma unroll
    for (int k = 0; k < 4; k++) {
      int qs = half * 4 + k;
      size_t qg = (size_t)b0 * NS + q0l + qs;
      aux[(size_t)(q0l + qs) * 96 + j] = acc[k] + qpos[qg * 3 + d];
    }
  }
  // q projection (scaled by sqrt(E)=8); wave g handles queries g*2, g*2+1
  {
    int e = tid & 63, g = tid >> 6;
    #pragma unroll
    for (int k = 0; k < 2; k++) {
      int qs = g * 2 + k;
      float a = b_q[e];
      for (int c = 0; c < FD; c++)
        a = fmaf(s_feat[qs * 260 + c], w_q[c * EDIM + e], a);
      s_q[qs * 68 + e] = a * 8.0f;
    }
  }
  __syncthreads();
  // qk: thread owns channel tid; w_k row contiguous (float4)
  {
    float acc[QT];
    #pragma unroll
    for (int qs = 0; qs < QT; qs++) acc[qs] = 0.f;
    const float4* wk4 = reinterpret_cast<const float4*>(w_k + (size_t)tid * EDIM);
    for (int e4 = 0; e4 < EDIM / 4; e4++) {
      float4 wv = wk4[e4];
      int e = e4 * 4;
      #pragma unroll
      for (int qs = 0; qs < QT; qs++) {
        acc[qs] = fmaf(s_q[qs * 68 + e + 0], wv.x, acc[qs]);
        acc[qs] = fmaf(s_q[qs * 68 + e + 1], wv.y, acc[qs]);
        acc[qs] = fmaf(s_q[qs * 68 + e + 2], wv.z, acc[qs]);
        acc[qs] = fmaf(s_q[qs * 68 + e + 3], wv.w, acc[qs]);
      }
    }
    #pragma unroll
    for (int qs = 0; qs < QT; qs++)
      qk[(size_t)(q0l + qs) * FD + tid] = acc[qs];
  }
}

// ---------------------------------------------------------------------------
// K3 (hot): 2 Morton-adjacent queries per block. Waves 0-1 -> query A,
// waves 2-3 -> query B; each wave samples 16 points (float4 per lane).
// af stored bf16 in LDS (wf path only; sim uses fp32 af in-register).
// LDS ~38 KB -> 4 blocks/CU.
// ---------------------------------------------------------------------------
__global__ __launch_bounds__(256) void attnk(
    const float* __restrict__ planesT, const float* __restrict__ aux,
    const float* __restrict__ qk, const unsigned* __restrict__ perm,
    float* __restrict__ wf)
{
  const int tid = threadIdx.x, lane = tid & 63, w = tid >> 6;
  const int bid = blockIdx.x;                 // 0..1023
  const int j = ((bid & 7) << 7) | (bid >> 3);
  const int c4 = lane * 4;

  __shared__ int     s_si[2][96][3];
  __shared__ float   s_sw[2][96][4];
  __shared__ float   s_sim[2][NP];
  __shared__ float   s_attn[2][NP];
  __shared__ ushort4 s_af[2 * NP * 64];       // 32 KB bf16: [q][point][lane]
  __shared__ int     s_q[2];

  if (tid < 2) s_q[tid] = (int)perm[2 * j + tid];
  __syncthreads();
  const int qw = s_q[w >> 1];                 // this wave's query
  const int blw = qw >> 10;

  if (tid < 192) {
    int qi = tid / 96, r = tid - qi * 96;
    int p = r / 3, pl = r - p * 3;
    int qq = s_q[qi];
    float ax = aux[(size_t)qq * 96 + p * 3 + 0];
    float ay = aux[(size_t)qq * 96 + p * 3 + 1];
    float az = aux[(size_t)qq * 96 + p * 3 + 2];
    float u = (pl == 2) ? ay : ax;   // pl0:(ax,az) pl1:(ax,ay) pl2:(ay,az)
    float v = (pl == 1) ? ay : az;
    setup_samp(s_si[qi][r], s_sw[qi][r], u, v);
  }
  float4 qk4 = *(const float4*)(qk + (size_t)qw * FD + c4);
  const float* P0 = planesT + 0 * (size_t)PPLANE + (size_t)blw * BATCH_ELEMS + c4;
  const float* P1 = planesT + 1 * (size_t)PPLANE + (size_t)blw * BATCH_ELEMS + c4;
  const float* P2 = planesT + 2 * (size_t)PPLANE + (size_t)blw * BATCH_ELEMS + c4;
  __syncthreads();

  const int qi = w >> 1;
  #pragma unroll 2
  for (int k = 0; k < 16; k++) {
    int p = (w & 1) * 16 + k;
    float4 a; a.x = 0.f; a.y = 0.f; a.z = 0.f; a.w = 0.f;
    #pragma unroll
    for (int pl = 0; pl < 3; pl++) {
      const float* P = pl == 0 ? P0 : (pl == 1 ? P1 : P2);
      int i00 = s_si[qi][p * 3 + pl][0];
      int dxo = s_si[qi][p * 3 + pl][1];
      int dyo = s_si[qi][p * 3 + pl][2];
      float w0 = s_sw[qi][p * 3 + pl][0], w1 = s_sw[qi][p * 3 + pl][1];
      float w2 = s_sw[qi][p * 3 + pl][2], w3 = s_sw[qi][p * 3 + pl][3];
      float4 f00 = *(const float4*)(P + i00);
      float4 f01 = *(const float4*)(P + i00 + dxo);
      float4 f10 = *(const float4*)(P + i00 + dyo);
      float4 f11 = *(const float4*)(P + i00 + dyo + dxo);
      a.x = fmaf(w0, f00.x, fmaf(w1, f01.x, fmaf(w2, f10.x, fmaf(w3, f11.x, a.x))));
      a.y = fmaf(w0, f00.y, fmaf(w1, f01.y, fmaf(w2, f10.y, fmaf(w3, f11.y, a.y))));
      a.z = fmaf(w0, f00.z, fmaf(w1, f01.z, fmaf(w2, f10.z, fmaf(w3, f11.z, a.z))));
      a.w = fmaf(w0, f00.w, fmaf(w1, f01.w, fmaf(w2, f10.w, fmaf(w3, f11.w, a.w))));
    }
    ushort4 h;
    h.x = f2bf(a.x); h.y = f2bf(a.y); h.z = f2bf(a.z); h.w = f2bf(a.w);
    s_af[(qi * NP + p) * 64 + lane] = h;
    float t = fmaf(qk4.x, a.x, fmaf(qk4.y, a.y, fmaf(qk4.z, a.z, qk4.w * a.w)));
    #pragma unroll
    for (int o = 32; o >= 1; o >>= 1) t += __shfl_xor(t, o, 64);
    if (lane == 0) s_sim[qi][p] = t;
  }
  __syncthreads();

  if (tid < 2 * NH) {   // softmax: qi=tid>>2, head h=tid&3 (points p=j*NH+h)
    int si = tid >> 2, h = tid & 3;
    float sim[SP3], m = -1e30f;
    #pragma unroll
    for (int jj = 0; jj < SP3; jj++) { sim[jj] = s_sim[si][jj * NH + h]; m = fmaxf(m, sim[jj]); }
    float sum = 0.f, e_[SP3];
    #pragma unroll
    for (int jj = 0; jj < SP3; jj++) { e_[jj] = __expf(sim[jj] - m); sum += e_[jj]; }
    float inv = 1.0f / sum;
    #pragma unroll
    for (int jj = 0; jj < SP3; jj++) s_attn[si][jj * NH + h] = e_[jj] * inv;
  }
  __syncthreads();

  { // wave w: query qi=w>>1, heads (w&1) and (w&1)+2
    #pragma unroll
    for (int hi = 0; hi < 2; hi++) {
      int h = (w & 1) + hi * 2;
      float4 r; r.x = 0.f; r.y = 0.f; r.z = 0.f; r.w = 0.f;
      #pragma unroll
      for (int jj = 0; jj < SP3; jj++) {
        int p = jj * NH + h;
        float a = s_attn[qi][p];
        ushort4 hv = s_af[(qi * NP + p) * 64 + lane];
        r.x = fmaf(a, bf2f(hv.x), r.x);
        r.y = fmaf(a, bf2f(hv.y), r.y);
        r.z = fmaf(a, bf2f(hv.z), r.z);
        r.w = fmaf(a, bf2f(hv.w), r.w);
      }
      *(float4*)(wf + ((size_t)qw * NH + h) * FD + c4) = r;
    }
  }
}

// ---------------------------------------------------------------------------
// K4: epilogue per 8-query tile: o = per-head wf@w_v + b_v (w_v in LDS),
// then out = o@w_out + b_out + feat (w_out streamed once per block).
// ---------------------------------------------------------------------------
__global__ __launch_bounds__(256) void epik(
    const float* __restrict__ wf, const float* __restrict__ feat,
    const float* __restrict__ w_v, const float* __restrict__ b_v,
    const float* __restrict__ w_out, const float* __restrict__ b_out,
    float* __restrict__ out, int b0)
{
  const int tid = threadIdx.x;
  const int q0l = blockIdx.x * QT;
  __shared__ float s_wv[FD * EDIM];   // 64 KB, [c][e]
  __shared__ float s_o[QT * 257];

  {
    const float4* src4 = (const float4*)w_v;
    float4* dst4 = (float4*)s_wv;
    #pragma unroll
    for (int i = 0; i < (FD * EDIM / 4) / 256; i++)
      dst4[tid + 256 * i] = src4[tid + 256 * i];
  }
  __syncthreads();

  { // phase A: o[qs][h*64+e]
    int h = tid >> 6, e = tid & 63;
    float acc[QT];
    float bv = b_v[e];
    #pragma unroll
    for (int qs = 0; qs < QT; qs++) acc[qs] = bv;
    const float* wrow = wf + ((size_t)q0l * NH + h) * FD;
    for (int c = 0; c < FD; c++) {
      float wv = s_wv[c * EDIM + e];
      #pragma unroll
      for (int qs = 0; qs < QT; qs++)
        acc[qs] = fmaf(wrow[(size_t)qs * NH * FD + c], wv, acc[qs]);
    }
    #pragma unroll
    for (int qs = 0; qs < QT; qs++) s_o[qs * 257 + h * EDIM + e] = acc[qs];
  }
  __syncthreads();

  { // phase B: out[q][d] = sum_c o[q][c] w_out[c][d] + b_out[d] + feat[q][d]
    float r[QT];
    float bo = b_out[tid];
    #pragma unroll
    for (int qs = 0; qs < QT; qs++) r[qs] = bo;
    for (int c = 0; c < FD; c++) {
      float wv = w_out[(size_t)c * FD + tid];
      #pragma unroll
      for (int qs = 0; qs < QT; qs++)
        r[qs] = fmaf(s_o[qs * 257 + c], wv, r[qs]);
    }
    #pragma unroll
    for (int qs = 0; qs < QT; qs++)
      out[((size_t)b0 * NS + q0l + qs) * FD + tid]
          = r[qs] + feat[(size_t)(q0l + qs) * FD + tid];
  }
}

// ---------------------------------------------------------------------------
extern "C" void kernel_launch(void* const* d_in, const int* in_sizes, int n_in,
                              void* d_out, int out_size, void* d_ws, size_t ws_size,
                              hipStream_t stream) {
  const float* qp    = (const float*)d_in[0];
  const float* cxz   = (const float*)d_in[1];
  const float* cxy   = (const float*)d_in[2];
  const float* cyz   = (const float*)d_in[3];
  const float* w_off = (const float*)d_in[4];
  const float* b_off = (const float*)d_in[5];
  const float* w_q   = (const float*)d_in[6];
  const float* b_q   = (const float*)d_in[7];
  const float* w_k   = (const float*)d_in[8];
  const float* b_k   = (const float*)d_in[9];   (void)b_k; // cancels in softmax
  const float* w_v   = (const float*)d_in[10];
  const float* b_v   = (const float*)d_in[11];
  const float* w_out = (const float*)d_in[12];
  const float* b_out = (const float*)d_in[13];
  float* out = (float*)d_out;
  (void)in_sizes; (void)n_in; (void)out_size; (void)ws_size;

  float* ws      = (float*)d_ws;
  float* planesT = ws + WS_PLANES;
  float* feat    = ws + WS_FEAT;
  float* qk      = ws + WS_QK;
  float* aux     = ws + WS_AUX;
  float* wf      = ws + WS_WF;
  unsigned* perm = (unsigned*)(ws + WS_PERM);

  hipLaunchKernelGGL(sortk, dim3(BS / PAIR_B), dim3(1024), 0, stream, qp, perm);

  for (int pair = 0; pair < BS / PAIR_B; ++pair) {
    int b0 = pair * PAIR_B;
    hipLaunchKernelGGL(tpk2, dim3(3 * PAIR_B * 512), dim3(256), 0, stream,
                       cxz, cxy, cyz, planesT, b0);
    hipLaunchKernelGGL(featk, dim3(PAIR_Q / QT), dim3(256), 0, stream,
                       qp, planesT, w_off, b_off, w_q, b_q, w_k,
                       feat, aux, qk, b0);
    hipLaunchKernelGGL(attnk, dim3(PAIR_Q / 2), dim3(256), 0, stream,
                       planesT, aux, qk, perm + (size_t)pair * PAIR_Q, wf);
    hipLaunchKernelGGL(epik, dim3(PAIR_Q / QT), dim3(256), 0, stream,
                       wf, feat, w_v, b_v, w_out, b_out, out, b0);
  }
}